// Round 7
// baseline (207.965 us; speedup 1.0000x reference)
//
#include <hip/hip_runtime.h>

#define NB   64
#define NT   256
#define NI   512
#define NO   512
#define NOBS 128
#define ETA  0.01f

typedef __attribute__((ext_vector_type(8))) short bf16x8;
typedef __attribute__((ext_vector_type(4))) float f32x4;

#define X4_COUNT  (NB*NT*NI/4)
#define WG4_COUNT (NB*NOBS*NI/4)
#define K0_TOTAL  (X4_COUNT + WG4_COUNT)

__device__ __forceinline__ unsigned short f2bf(float f) {
    unsigned int u = __float_as_uint(f);
    return (unsigned short)((u + 0x7fffu + ((u >> 16) & 1u)) >> 16); // RNE
}

// ---------------- K0: X -> bf16 ; gather obs rows of W -> bf16 ----------------
__global__ __launch_bounds__(256)
void k0_convert(const float* __restrict__ X, const float* __restrict__ Wi,
                const int* __restrict__ obs,
                unsigned short* __restrict__ Xb, unsigned short* __restrict__ Wg)
{
    int idx = blockIdx.x * 256 + threadIdx.x;
    const int stride = gridDim.x * 256;
    for (; idx < K0_TOTAL; idx += stride) {
        float4 v; ushort4* dst;
        if (idx < X4_COUNT) {
            v = ((const float4*)X)[idx];
            dst = (ushort4*)Xb + idx;
        } else {
            int g = idx - X4_COUNT;
            int row = g >> 7, pos = g & 127;
            int b = row >> 7, j = row & 127;
            v = ((const float4*)(Wi + ((size_t)b * NO + obs[j]) * NI))[pos];
            dst = (ushort4*)Wg + ((size_t)row * 128 + pos);
        }
        *dst = make_ushort4(f2bf(v.x), f2bf(v.y), f2bf(v.z), f2bf(v.w));
    }
}

// ---------------- K1: LDS-tiled bf16 MFMA GEMM ----------------
// 6 blocks per batch: sub 0..3 -> G 128-blocks (bm=sub>>1, bn=sub&1)  [full G]
//                     sub 4..5 -> P0 row-blocks {0,1}
__global__ __launch_bounds__(256)
void k1_gemm(const unsigned short* __restrict__ Xb,
             const unsigned short* __restrict__ Wg,
             float* __restrict__ G, float* __restrict__ P0)
{
    __shared__ unsigned short As[128 * 64];
    __shared__ unsigned short Bs[128 * 64];

    const int tid  = threadIdx.x;
    const int lane = tid & 63;
    const int wv   = tid >> 6;
    const int l16  = lane & 15;
    const int quad = lane >> 4;

    // swizzle: same-batch blocks 64 apart -> same XCD for L2 reuse of Xb
    const int b   = blockIdx.x & 63;
    const int sub = blockIdx.x >> 6;

    const unsigned short* xbB = Xb + (size_t)b * NT * NI;
    const unsigned short *aRows, *bRows;
    float* outp;
    int ldo;
    if (sub < 4) {
        const int bm = sub >> 1, bn = sub & 1;
        aRows = xbB + (size_t)bm * 128 * NI;
        bRows = xbB + (size_t)bn * 128 * NI;
        outp  = G + (size_t)b * NT * NT + (size_t)bm * 128 * NT + bn * 128;
        ldo   = NT;
    } else {
        const int pb = sub - 4;
        aRows = xbB + (size_t)pb * 128 * NI;
        bRows = Wg + (size_t)b * NOBS * NI;
        outp  = P0 + (size_t)b * NT * NOBS + (size_t)pb * 128 * NOBS;
        ldo   = NOBS;
    }

    const int wm = (wv >> 1) * 64;
    const int wn = (wv & 1) * 64;

    f32x4 acc[4][4] = {};

    for (int kb = 0; kb < NI / 64; ++kb) {
        __syncthreads();
#pragma unroll
        for (int it = 0; it < 4; ++it) {
            const int s = it * 256 + tid;
            const int m = s >> 3, c = s & 7;
            const int slot = m * 64 + ((c ^ (m & 7)) * 8);
            const size_t goff = (size_t)m * NI + kb * 64 + c * 8;
            *(bf16x8*)&As[slot] = *(const bf16x8*)(aRows + goff);
            *(bf16x8*)&Bs[slot] = *(const bf16x8*)(bRows + goff);
        }
        __syncthreads();
#pragma unroll
        for (int ks = 0; ks < 2; ++ks) {
            const int q = ks * 4 + quad;
            bf16x8 af[4], bfr[4];
#pragma unroll
            for (int mt = 0; mt < 4; ++mt) {
                const int m = wm + mt * 16 + l16;
                af[mt] = *(const bf16x8*)&As[m * 64 + ((q ^ (m & 7)) * 8)];
            }
#pragma unroll
            for (int nt = 0; nt < 4; ++nt) {
                const int n = wn + nt * 16 + l16;
                bfr[nt] = *(const bf16x8*)&Bs[n * 64 + ((q ^ (n & 7)) * 8)];
            }
#pragma unroll
            for (int mt = 0; mt < 4; ++mt)
#pragma unroll
                for (int nt = 0; nt < 4; ++nt)
                    acc[mt][nt] = __builtin_amdgcn_mfma_f32_16x16x32_bf16(
                        af[mt], bfr[nt], acc[mt][nt], 0, 0, 0);
        }
    }

#pragma unroll
    for (int mt = 0; mt < 4; ++mt)
#pragma unroll
        for (int nt = 0; nt < 4; ++nt)
#pragma unroll
            for (int r = 0; r < 4; ++r)
                outp[(size_t)(wm + mt * 16 + quad * 4 + r) * ldo
                     + wn + nt * 16 + l16] = acc[mt][nt][r];
}

// ---------------- K2: pipelined blocked forward-substitution scan ----------------
// block = (b, 32 j's). pre[256][32] in LDS. Per chunk c:
//  P1: wave0 lanes 0-31: serial 16 sigmoid steps (all 32 j's, diag-G broadcast)
//      waves 1-3: lazy-apply Y_{c-1} to chunks >= c+2 (G rows contiguous 64B)
//  P2: all waves: eager-apply Y_c to chunks c+1, c+2.
// Coverage: chunk m gets Y_{m-1},Y_{m-2} eagerly, Y_{<=m-3} lazily. Complete.
__global__ __launch_bounds__(256)
void k2_scan(const float* __restrict__ G, const float* __restrict__ P0,
             float* __restrict__ out)
{
    __shared__ float preL[256 * 32];       // 32 KB [t][j]
    __shared__ float yb[2][16 * 32];       //  4 KB ping-pong y
    __shared__ float gdiag[16 * 16 * 16];  // 16 KB [c][u][v]

    const int tid = threadIdx.x;
    // swizzle: same-batch blocks 64 apart -> same XCD (L2 reuse of G, P0)
    const int b  = blockIdx.x & 63;
    const int jb = blockIdx.x >> 6;        // 0..3

    const float* Gb = G  + (size_t)b * NT * NT;
    const float* Pb = P0 + (size_t)b * NT * NOBS + jb * 32;
    float*       ob = out + (size_t)b * NT * NOBS + jb * 32;

    // ---- init: P0 chunk -> preL ; G diag 16-blocks -> gdiag ----
#pragma unroll
    for (int p = 0; p < 8; ++p) {
        const int i = p * 256 + tid;
        ((f32x4*)preL)[i] =
            *(const f32x4*)(Pb + (size_t)(i >> 3) * NOBS + (i & 7) * 4);
    }
#pragma unroll
    for (int p = 0; p < 4; ++p) {
        const int fi = p * 256 + tid;
        const int c = fi >> 6, u = (fi >> 2) & 15, v4 = fi & 3;
        ((f32x4*)gdiag)[fi] =
            *(const f32x4*)(Gb + (size_t)(c * 16 + u) * NT + c * 16 + v4 * 4);
    }
    __syncthreads();

    const int j = tid & 31;

    for (int c = 0; c < 16; ++c) {
        const int cp = c & 1;
        // ---------------- P1 ----------------
        if (tid < 64) {
            if (tid < 32) {  // serial phase, lane = j
                float pre[16];
#pragma unroll
                for (int u = 0; u < 16; ++u) pre[u] = preL[(c * 16 + u) * 32 + j];
                const float* gd = gdiag + c * 256;
#pragma unroll
                for (int u = 0; u < 16; ++u) {
                    const float y = 1.f / (1.f + __expf(-pre[u]));
                    yb[cp][u * 32 + j] = y;
                    ob[(size_t)(c * 16 + u) * NOBS + j] = y;
                    const float e = ETA * y;
#pragma unroll
                    for (int v = u + 1; v < 16; ++v)
                        pre[v] = fmaf(e, gd[u * 16 + v], pre[v]);
                }
            }
        } else if (c >= 1) {  // lazy phase: waves 1-3, 6 groups of 32
            const int g = (tid >> 5) - 2;
            float ey[16];
#pragma unroll
            for (int u = 0; u < 16; ++u) ey[u] = ETA * yb[cp ^ 1][u * 32 + j];
            const int kcol = (c - 1) * 16;
            for (int t = c * 16 + 32 + g; t < NT; t += 6) {
                f32x4 gq[4];
                const f32x4* gr = (const f32x4*)(Gb + (size_t)t * NT + kcol);
#pragma unroll
                for (int q = 0; q < 4; ++q) gq[q] = gr[q];
                float acc = preL[t * 32 + j];
                const float* gv = (const float*)gq;
#pragma unroll
                for (int u = 0; u < 16; ++u) acc = fmaf(ey[u], gv[u], acc);
                preL[t * 32 + j] = acc;
            }
        }
        __syncthreads();
        // ---------------- P2: eager Y_c -> chunks c+1, c+2 ----------------
        {
            const int g = tid >> 5;  // 0..7
            float ey[16];
#pragma unroll
            for (int u = 0; u < 16; ++u) ey[u] = ETA * yb[cp][u * 32 + j];
            const int kcol = c * 16;
            const int tend = (c * 16 + 48 < NT) ? c * 16 + 48 : NT;
            for (int t = c * 16 + 16 + g; t < tend; t += 8) {
                f32x4 gq[4];
                const f32x4* gr = (const f32x4*)(Gb + (size_t)t * NT + kcol);
#pragma unroll
                for (int q = 0; q < 4; ++q) gq[q] = gr[q];
                float acc = preL[t * 32 + j];
                const float* gv = (const float*)gq;
#pragma unroll
                for (int u = 0; u < 16; ++u) acc = fmaf(ey[u], gv[u], acc);
                preL[t * 32 + j] = acc;
            }
        }
        __syncthreads();
    }
}

extern "C" void kernel_launch(void* const* d_in, const int* in_sizes, int n_in,
                              void* d_out, int out_size, void* d_ws, size_t ws_size,
                              hipStream_t stream)
{
    const float* X   = (const float*)d_in[0];
    const float* Wi  = (const float*)d_in[1];
    const int*   obs = (const int*)d_in[2];
    float*       out = (float*)d_out;

    unsigned short* Xb = (unsigned short*)d_ws;                          // 16 MB
    unsigned short* Wg = (unsigned short*)((char*)d_ws + (16u << 20));   //  8 MB
    float*          G  = (float*)((char*)d_ws + (24u << 20));            // 16 MB
    float*          P0 = (float*)((char*)d_ws + (40u << 20));            //  8 MB

    hipLaunchKernelGGL(k0_convert, dim3(3072), dim3(256), 0, stream,
                       X, Wi, obs, Xb, Wg);
    hipLaunchKernelGGL(k1_gemm, dim3(NB * 6), dim3(256), 0, stream,
                       Xb, Wg, G, P0);
    hipLaunchKernelGGL(k2_scan, dim3(NB * 4), dim3(256), 0, stream,
                       G, P0, out);
}